// Round 13
// baseline (106.892 us; speedup 1.0000x reference)
//
#include <hip/hip_runtime.h>

// Problem constants: B=256, T=256, H=768, S=130
#define BB 256
#define TT 256
#define HH 768
#define SS 130
#define NPH 12                   // K phases of 64
#define SLU 4608                 // uints per wsT2 slice: 144 rows x 32 uints (18432 B)

typedef __attribute__((ext_vector_type(8))) __bf16 bf16x8;
typedef __attribute__((ext_vector_type(4))) float f32x4;

__device__ __forceinline__ unsigned f2bf(float f) {
    unsigned x = __builtin_bit_cast(unsigned, f);
    x = (x + 0x7FFFu + ((x >> 16) & 1u)) >> 16;
    return x & 0xFFFFu;
}
__device__ __forceinline__ float bf2f(unsigned short u) {
    return __builtin_bit_cast(float, (unsigned)u << 16);
}

// ---- prep: [0..107] W -> wsT2 [12][144 s][64 k bf16], 16B-slot j at j^(s&7);
//            [108..363] seg -> bounds {start,count} ----
__global__ __launch_bounds__(256)
void prep_kernel(const float* __restrict__ W, unsigned* __restrict__ wsT2,
                 const int* __restrict__ seg, int2* __restrict__ bounds)
{
    __shared__ __align__(16) char pm[64 * 17 * 4];     // 4352 B
    const int tid = threadIdx.x;

    if (blockIdx.x < 108) {
        float* Wl = (float*)pm;                        // [64 k][17]
        const int kc    = blockIdx.x / 9;              // slice 0..11
        const int g16   = blockIdx.x % 9;              // s-group of 16
        const int sbase = g16 * 16;
        const int scv   = (SS - sbase < 16) ? (SS - sbase) : 16;
        for (int i = tid; i < 64 * 16; i += 256) {
            int r = i >> 4, c = i & 15;
            float v = 0.f;
            if (c < scv) v = W[(size_t)(kc * 64 + r) * SS + sbase + c];
            Wl[r * 17 + c] = v;
        }
        __syncthreads();
        for (int i = tid; i < 16 * 32; i += 256) {     // coalesced 128B-row writes
            int sl = i >> 5, qu = i & 31;
            int s  = sbase + sl;
            int qp = qu >> 2, m = qu & 3;
            int j  = qp ^ (s & 7);                     // logical 16B slot (3-bit involution)
            int kp = j * 4 + m;                        // k-pair 0..31 within slice
            unsigned v = 0;
            if (sl < scv)
                v = f2bf(Wl[(2 * kp) * 17 + sl]) | (f2bf(Wl[(2 * kp + 1) * 17 + sl]) << 16);
            wsT2[kc * SLU + s * 32 + qu] = v;
        }
    } else {
        int* segl = (int*)pm;
        int* st_s = segl + 256;
        int* cn_s = segl + 512;
        const int b = blockIdx.x - 108;
        segl[tid] = seg[b * TT + tid];
        st_s[tid] = 0;
        cn_s[tid] = 0;
        __syncthreads();
        int id = segl[tid];
        if (tid == 0 || segl[tid - 1] != id) {         // run starts (seg row-sorted)
            int e = tid;
            while (e + 1 < TT && segl[e + 1] == id) ++e;
            st_s[id] = tid;
            cn_s[id] = e - tid + 1;
        }
        __syncthreads();
        bounds[b * TT + tid] = make_int2(st_s[tid], cn_s[tid]);
    }
}

// ---- K1: 12-phase double-buffered GEMM, counted vmcnt(4), raw barriers ----
__global__ __launch_bounds__(256, 4)
void gemm_kernel(const float* __restrict__ hidden, const unsigned* __restrict__ wsT2,
                 const float* __restrict__ bias, unsigned short* __restrict__ logits)
{
    __shared__ __align__(16) unsigned Blds[2 * SLU];   // 36864 B -> 4 blocks/CU

    const int tid  = threadIdx.x;
    const int wv   = tid >> 6;
    const int lane = tid & 63;
    const int r16  = lane & 15;
    const int g    = lane >> 4;
    const int b    = blockIdx.x >> 2;
    const int tb   = (blockIdx.x & 3) << 6;
    const int obase = 4 * wv + (wv >> 1);              // 0,4,9,13 (1KB units)

    const float* Abase = hidden + (size_t)b * (TT + 1) * HH
                       + (size_t)(1 + tb + wv * 16 + r16) * HH + g * 8;

    f32x4 acc[9];
    #pragma unroll
    for (int j = 0; j < 9; ++j) acc[j] = (f32x4){0.f, 0.f, 0.f, 0.f};

// 18 KB slice split 4/5/4/5 across waves; dest linear, src pre-swizzled
#define DMA12(P, BUF)                                                                     \
    do {                                                                                  \
        const unsigned* gs_ = wsT2 + (size_t)(P) * SLU + obase * 256 + lane * 4;          \
        unsigned* ld_ = Blds + (BUF) * SLU + obase * 256;                                 \
        _Pragma("unroll")                                                                 \
        for (int i_ = 0; i_ < 4; ++i_)                                                    \
            __builtin_amdgcn_global_load_lds(gs_ + i_ * 256, ld_ + i_ * 256, 16, 0, 0);   \
        if (wv & 1)                                                                       \
            __builtin_amdgcn_global_load_lds(gs_ + 4 * 256, ld_ + 4 * 256, 16, 0, 0);     \
    } while (0)

#define LOADA(X0, X1, X2, X3, P)                                                          \
    do {                                                                                  \
        const float* ap_ = Abase + (P) * 64;                                              \
        X0 = *(const float4*)(ap_);        X1 = *(const float4*)(ap_ + 4);                \
        X2 = *(const float4*)(ap_ + 32);   X3 = *(const float4*)(ap_ + 36);               \
    } while (0)

// one K=32 chunk: 9 MFMA from swizzled LDS (slot (c*4+g)^(r16&7); row nt*16+r16)
#define MCHUNK(AF, C_, BUF)                                                               \
    do {                                                                                  \
        const char* bp_ = (const char*)Blds + (BUF) * 18432 + r16 * 128                   \
                        + ((((C_) * 4 + g) ^ (r16 & 7)) << 4);                            \
        _Pragma("unroll")                                                                 \
        for (int nt = 0; nt < 9; ++nt)                                                    \
            acc[nt] = __builtin_amdgcn_mfma_f32_16x16x32_bf16(                            \
                AF.v, *(const bf16x8*)(bp_ + nt * 2048), acc[nt], 0, 0, 0);               \
    } while (0)

// phase P: counted wait -> barrier -> DMA(P+1) -> cvt A(P) -> LOADA(P+2) -> 2 chunks
#define PHASE(E0, E1, E2, E3, P, BUF)                                                     \
    do {                                                                                  \
        asm volatile("s_waitcnt vmcnt(4)" ::: "memory");                                  \
        __builtin_amdgcn_s_barrier();                                                     \
        __builtin_amdgcn_sched_barrier(0);                                                \
        { const int pn_ = ((P) + 1 < NPH) ? (P) + 1 : NPH - 1;                            \
          DMA12(pn_, (BUF) ^ 1); }                                                        \
        union { unsigned u[4]; bf16x8 v; } af0_, af1_;                                    \
        asm("v_cvt_pk_bf16_f32 %0, %1, %2" : "=v"(af0_.u[0]) : "v"(E0.x), "v"(E0.y));     \
        asm("v_cvt_pk_bf16_f32 %0, %1, %2" : "=v"(af0_.u[1]) : "v"(E0.z), "v"(E0.w));     \
        asm("v_cvt_pk_bf16_f32 %0, %1, %2" : "=v"(af0_.u[2]) : "v"(E1.x), "v"(E1.y));     \
        asm("v_cvt_pk_bf16_f32 %0, %1, %2" : "=v"(af0_.u[3]) : "v"(E1.z), "v"(E1.w));     \
        asm("v_cvt_pk_bf16_f32 %0, %1, %2" : "=v"(af1_.u[0]) : "v"(E2.x), "v"(E2.y));     \
        asm("v_cvt_pk_bf16_f32 %0, %1, %2" : "=v"(af1_.u[1]) : "v"(E2.z), "v"(E2.w));     \
        asm("v_cvt_pk_bf16_f32 %0, %1, %2" : "=v"(af1_.u[2]) : "v"(E3.x), "v"(E3.y));     \
        asm("v_cvt_pk_bf16_f32 %0, %1, %2" : "=v"(af1_.u[3]) : "v"(E3.z), "v"(E3.w));     \
        { const int pa_ = ((P) + 2 < NPH) ? (P) + 2 : NPH - 1;                            \
          LOADA(E0, E1, E2, E3, pa_); }                                                   \
        MCHUNK(af0_, 0, BUF); MCHUNK(af1_, 1, BUF);                                       \
    } while (0)

    // prologue: B_0 DMA into buf0; A_0 (even set), A_1 (odd set)
    DMA12(0, 0);
    float4 e0, e1, e2, e3, o0, o1, o2, o3;
    LOADA(e0, e1, e2, e3, 0);
    LOADA(o0, o1, o2, o3, 1);

    #pragma unroll 1
    for (int pp = 0; pp < NPH / 2; ++pp) {
        PHASE(e0, e1, e2, e3, 2 * pp, 0);
        PHASE(o0, o1, o2, o3, 2 * pp + 1, 1);
    }
#undef PHASE
#undef MCHUNK
#undef LOADA
#undef DMA12

    asm volatile("s_waitcnt vmcnt(0)" ::: "memory");   // drain clamped tail loads

    // epilogue: +bias, bf16 store [b][s][t], t-contiguous ushort4 per lane
    const int tq = tb + wv * 16 + g * 4;               // D row = g*4 + i
    #pragma unroll
    for (int nt = 0; nt < 9; ++nt) {
        int s = nt * 16 + r16;                          // D col = r16
        if (s < SS) {
            float bs = bias[s];
            ushort4 v;
            v.x = (unsigned short)f2bf(acc[nt][0] + bs);
            v.y = (unsigned short)f2bf(acc[nt][1] + bs);
            v.z = (unsigned short)f2bf(acc[nt][2] + bs);
            v.w = (unsigned short)f2bf(acc[nt][3] + bs);
            *(ushort4*)(logits + ((size_t)b * SS + s) * TT + tq) = v;
        }
    }
}

// ---- K2: barrier-free ragged segment-mean (bf16 logits -> f32 out) ----
__global__ __launch_bounds__(256)
void merge_kernel(const int2* __restrict__ bounds,
                  const unsigned short* __restrict__ logits,
                  float* __restrict__ out)
{
    const int blk = blockIdx.x;          // 256 * 65
    const int b   = blk / 65;
    const int sp  = (blk - b * 65) * 2;
    const int w   = threadIdx.x;

    const int2 bc = bounds[b * TT + w];  // {start, count}
    const float inv = (bc.y > 0) ? 1.f / (float)bc.y : 0.f;

    #pragma unroll
    for (int i = 0; i < 2; ++i) {
        const int s = sp + i;            // 130 = 65*2, always valid
        const unsigned short* row = logits + ((size_t)b * SS + s) * TT;
        float a = 0.f;
        for (int k = 0; k < bc.y; ++k) a += bf2f(row[bc.x + k]);
        out[((size_t)b * SS + s) * TT + w] = a * inv;
    }
}

extern "C" void kernel_launch(void* const* d_in, const int* in_sizes, int n_in,
                              void* d_out, int out_size, void* d_ws, size_t ws_size,
                              hipStream_t stream)
{
    const float* hidden = (const float*)d_in[0];  // [256, 257, 768] f32
    const float* W      = (const float*)d_in[1];  // [768, 130] f32
    const float* bias   = (const float*)d_in[2];  // [130] f32
    const int*   seg    = (const int*)d_in[3];    // [256, 256] i32 (row-sorted)
    float* out = (float*)d_out;                   // [256, 130, 256] f32

    unsigned*       wsT2   = (unsigned*)d_ws;                        // 221184 B
    int2*           bounds = (int2*)((char*)d_ws + 221184);          // 524288 B
    unsigned short* logits = (unsigned short*)((char*)d_ws + 221184 + 524288);  // 17039360 B

    (void)in_sizes; (void)n_in; (void)ws_size; (void)out_size;

    prep_kernel<<<dim3(364), dim3(256), 0, stream>>>(W, wsT2, seg, bounds);
    gemm_kernel<<<dim3(BB * 4), dim3(256), 0, stream>>>(hidden, wsT2, bias, logits);
    merge_kernel<<<dim3(BB * 65), dim3(256), 0, stream>>>(bounds, logits, out);
}

// Round 14
// 80.554 us; speedup vs baseline: 1.3270x; 1.3270x over previous
//
#include <hip/hip_runtime.h>

// Problem constants: B=256, T=256, H=768, S=130
#define BB 256
#define TT 256
#define HH 768
#define SS 130
#define NPH 6                    // K phases of 128
#define SROWS 144                // 9 n-tiles x 16 rows per B slice
#define SLU (SROWS * 64)         // uints per wsT2 phase slice = 9216 (36864 B)
#define MSP 10                   // merge: s-rows per block (130 = 13*10)

typedef __attribute__((ext_vector_type(8))) __bf16 bf16x8;
typedef __attribute__((ext_vector_type(4))) float f32x4;

__device__ __forceinline__ unsigned f2bf(float f) {
    unsigned x = __builtin_bit_cast(unsigned, f);
    x = (x + 0x7FFFu + ((x >> 16) & 1u)) >> 16;
    return x & 0xFFFFu;
}
__device__ __forceinline__ float bf2f(unsigned short u) {
    return __builtin_bit_cast(float, (unsigned)u << 16);
}

// ---- prep: [0..53] W -> wsT2 [6][144 s][128 k bf16], 16B-slot j at j^(s&15);
//            [54..309] seg -> bounds {start,count} ----
__global__ __launch_bounds__(256)
void prep_kernel(const float* __restrict__ W, unsigned* __restrict__ wsT2,
                 const int* __restrict__ seg, int2* __restrict__ bounds)
{
    __shared__ __align__(16) char pm[128 * 17 * 4];   // 8704 B
    const int tid = threadIdx.x;

    if (blockIdx.x < 54) {
        float* Wl = (float*)pm;                        // [128 k][17]
        const int kc6   = blockIdx.x / 9;              // phase 0..5
        const int g16   = blockIdx.x % 9;              // s-group of 16
        const int sbase = g16 * 16;
        const int scv   = (SS - sbase < 16) ? (SS - sbase) : 16;
        for (int i = tid; i < 128 * 16; i += 256) {
            int r = i >> 4, c = i & 15;
            float v = 0.f;
            if (c < scv) v = W[(size_t)(kc6 * 128 + r) * SS + sbase + c];
            Wl[r * 17 + c] = v;
        }
        __syncthreads();
        for (int i = tid; i < 16 * 64; i += 256) {     // coalesced 256B-row writes
            int sl = i >> 6, qu = i & 63;
            int s  = sbase + sl;
            int qp = qu >> 2, m = qu & 3;
            int j  = qp ^ (s & 15);                    // logical 16B slot (involution)
            int kp = j * 4 + m;                        // k-pair 0..63 within slice
            unsigned v = 0;
            if (sl < scv)
                v = f2bf(Wl[(2 * kp) * 17 + sl]) | (f2bf(Wl[(2 * kp + 1) * 17 + sl]) << 16);
            wsT2[kc6 * SLU + s * 64 + qu] = v;
        }
    } else {
        int* segl = (int*)pm;
        int* st_s = segl + 256;
        int* cn_s = segl + 512;
        const int b = blockIdx.x - 54;
        segl[tid] = seg[b * TT + tid];
        st_s[tid] = 0;
        cn_s[tid] = 0;
        __syncthreads();
        int id = segl[tid];
        if (tid == 0 || segl[tid - 1] != id) {         // run starts (seg row-sorted)
            int e = tid;
            while (e + 1 < TT && segl[e + 1] == id) ++e;
            st_s[id] = tid;
            cn_s[id] = e - tid + 1;
        }
        __syncthreads();
        bounds[b * TT + tid] = make_int2(st_s[tid], cn_s[tid]);
    }
}

// ---- K1 (= R12): 6-phase single-buffer GEMM, 144-row B slices, bf16 out ----
__global__ __launch_bounds__(256, 4)
void gemm_kernel(const float* __restrict__ hidden, const unsigned* __restrict__ wsT2,
                 const float* __restrict__ bias, unsigned short* __restrict__ logits)
{
    __shared__ __align__(16) unsigned Blds[SLU];       // 36864 B -> 4 blocks/CU

    const int tid  = threadIdx.x;
    const int wv   = tid >> 6;
    const int lane = tid & 63;
    const int r16  = lane & 15;
    const int g    = lane >> 4;
    const int b    = blockIdx.x >> 2;
    const int tb   = (blockIdx.x & 3) << 6;
    const float* Abase = hidden + (size_t)b * (TT + 1) * HH
                       + (size_t)(1 + tb + wv * 16 + r16) * HH + g * 8;

    f32x4 acc[9];
    #pragma unroll
    for (int j = 0; j < 9; ++j) acc[j] = (f32x4){0.f, 0.f, 0.f, 0.f};

#define DMA9(P)                                                                           \
    do {                                                                                  \
        const unsigned* gs_ = wsT2 + (size_t)(P) * SLU + wv * 2304 + lane * 4;            \
        unsigned* ld_ = Blds + wv * 2304;                                                 \
        _Pragma("unroll")                                                                 \
        for (int i_ = 0; i_ < 9; ++i_)                                                    \
            __builtin_amdgcn_global_load_lds(gs_ + i_ * 256, ld_ + i_ * 256, 16, 0, 0);   \
    } while (0)

#define LOADA(X0, X1, X2, X3, X4, X5, X6, X7, P)                                          \
    do {                                                                                  \
        const float* ap_ = Abase + (P) * 128;                                             \
        X0 = *(const float4*)(ap_);        X1 = *(const float4*)(ap_ + 4);                \
        X2 = *(const float4*)(ap_ + 32);   X3 = *(const float4*)(ap_ + 36);               \
        X4 = *(const float4*)(ap_ + 64);   X5 = *(const float4*)(ap_ + 68);               \
        X6 = *(const float4*)(ap_ + 96);   X7 = *(const float4*)(ap_ + 100);              \
    } while (0)

#define CHUNKC(Ea, Eb, C_)                                                                \
    do {                                                                                  \
        union { unsigned u[4]; bf16x8 v; } af_;                                           \
        asm("v_cvt_pk_bf16_f32 %0, %1, %2" : "=v"(af_.u[0]) : "v"(Ea.x), "v"(Ea.y));      \
        asm("v_cvt_pk_bf16_f32 %0, %1, %2" : "=v"(af_.u[1]) : "v"(Ea.z), "v"(Ea.w));      \
        asm("v_cvt_pk_bf16_f32 %0, %1, %2" : "=v"(af_.u[2]) : "v"(Eb.x), "v"(Eb.y));      \
        asm("v_cvt_pk_bf16_f32 %0, %1, %2" : "=v"(af_.u[3]) : "v"(Eb.z), "v"(Eb.w));      \
        const char* bp_ = (const char*)Blds + r16 * 256 + ((((C_) * 4 + g) ^ r16) << 4);  \
        _Pragma("unroll")                                                                 \
        for (int nt = 0; nt < 9; ++nt)                                                    \
            acc[nt] = __builtin_amdgcn_mfma_f32_16x16x32_bf16(                            \
                af_.v, *(const bf16x8*)(bp_ + nt * 4096), acc[nt], 0, 0, 0);              \
    } while (0)

#define PHASE(C0, C1, C2, C3, C4, C5, C6, C7, N0, N1, N2, N3, N4, N5, N6, N7, P)          \
    do {                                                                                  \
        __syncthreads();                                                                  \
        DMA9(P);                                                                          \
        asm volatile("s_waitcnt vmcnt(0)" ::: "memory");                                  \
        __syncthreads();                                                                  \
        { const int pn_ = ((P) + 1 < NPH) ? (P) + 1 : NPH - 1;                            \
          LOADA(N0, N1, N2, N3, N4, N5, N6, N7, pn_); }                                   \
        CHUNKC(C0, C1, 0); CHUNKC(C2, C3, 1); CHUNKC(C4, C5, 2); CHUNKC(C6, C7, 3);       \
    } while (0)

    float4 e0, e1, e2, e3, e4, e5, e6, e7;
    float4 o0, o1, o2, o3, o4, o5, o6, o7;
    LOADA(e0, e1, e2, e3, e4, e5, e6, e7, 0);
    #pragma unroll 1
    for (int pp = 0; pp < 3; ++pp) {
        PHASE(e0, e1, e2, e3, e4, e5, e6, e7, o0, o1, o2, o3, o4, o5, o6, o7, 2 * pp);
        PHASE(o0, o1, o2, o3, o4, o5, o6, o7, e0, e1, e2, e3, e4, e5, e6, e7, 2 * pp + 1);
    }
#undef PHASE
#undef CHUNKC
#undef LOADA
#undef DMA9

    // epilogue: +bias, bf16 store [b][s][t], t-contiguous ushort4 per lane
    const int tq = tb + wv * 16 + g * 4;               // D row = g*4 + i
    #pragma unroll
    for (int nt = 0; nt < 9; ++nt) {
        int s = nt * 16 + r16;                          // D col = r16
        if (s < SS) {
            float bs = bias[s];
            ushort4 v;
            v.x = (unsigned short)f2bf(acc[nt][0] + bs);
            v.y = (unsigned short)f2bf(acc[nt][1] + bs);
            v.z = (unsigned short)f2bf(acc[nt][2] + bs);
            v.w = (unsigned short)f2bf(acc[nt][3] + bs);
            *(ushort4*)(logits + ((size_t)b * SS + s) * TT + tq) = v;
        }
    }
}

// ---- K2: barrier-free ragged segment-mean; 10 s-rows per block (bounds amortized) ----
__global__ __launch_bounds__(256)
void merge_kernel(const int2* __restrict__ bounds,
                  const unsigned short* __restrict__ logits,
                  float* __restrict__ out)
{
    const int blk = blockIdx.x;          // 256 * 13
    const int b   = blk / 13;
    const int sp  = (blk - b * 13) * MSP;
    const int w   = threadIdx.x;

    const int2 bc = bounds[b * TT + w];  // {start, count} — loaded once per 10 rows
    float* obase = out + ((size_t)b * SS + sp) * TT + w;

    if (bc.y <= 0) {                     // empty word: zeros, no logits touched
        #pragma unroll
        for (int i = 0; i < MSP; ++i) obase[(size_t)i * TT] = 0.f;
        return;
    }
    const float inv = 1.f / (float)bc.y;
    const unsigned short* rbase = logits + ((size_t)b * SS + sp) * TT + bc.x;

    #pragma unroll
    for (int i = 0; i < MSP; ++i) {      // sp+i < 130 always (130 = 13*10)
        const unsigned short* row = rbase + (size_t)i * TT;
        float a = 0.f;
        for (int k = 0; k < bc.y; ++k) a += bf2f(row[k]);
        obase[(size_t)i * TT] = a * inv;
    }
}

extern "C" void kernel_launch(void* const* d_in, const int* in_sizes, int n_in,
                              void* d_out, int out_size, void* d_ws, size_t ws_size,
                              hipStream_t stream)
{
    const float* hidden = (const float*)d_in[0];  // [256, 257, 768] f32
    const float* W      = (const float*)d_in[1];  // [768, 130] f32
    const float* bias   = (const float*)d_in[2];  // [130] f32
    const int*   seg    = (const int*)d_in[3];    // [256, 256] i32 (row-sorted)
    float* out = (float*)d_out;                   // [256, 130, 256] f32

    unsigned*       wsT2   = (unsigned*)d_ws;                        // 221184 B
    int2*           bounds = (int2*)((char*)d_ws + 221184);          // 524288 B
    unsigned short* logits = (unsigned short*)((char*)d_ws + 221184 + 524288);  // 17039360 B

    (void)in_sizes; (void)n_in; (void)ws_size; (void)out_size;

    prep_kernel<<<dim3(310), dim3(256), 0, stream>>>(W, wsT2, seg, bounds);
    gemm_kernel<<<dim3(BB * 4), dim3(256), 0, stream>>>(hidden, wsT2, bias, logits);
    merge_kernel<<<dim3(BB * 13), dim3(256), 0, stream>>>(bounds, logits, out);
}